// Round 2
// baseline (1317.965 us; speedup 1.0000x reference)
//
#include <hip/hip_runtime.h>
#include <stdint.h>
#include <math.h>

#define THREADS 256
#define NBINS   2048
#define CAP     2048
#define SORTN   2048
#define C_CLS   30
#define H_      128
#define W_      128
#define HW_     (H_*W_)            // 16384
#define PER_IMG (C_CLS*HW_)        // 491520
#define TH      0.3f
#define XMIN    -0.8475f           // conservative pre-filter: logit(0.3) = -0.84729786
#define BIN_SCALE ((float)NBINS / 0.7f)

__device__ __forceinline__ float sigmoid_rn(float x) {
    // double-precision eval -> correctly-rounded f32 sigmoid (order matches a f32 reference)
    return (float)(1.0 / (1.0 + exp(-(double)x)));
}

__device__ __forceinline__ int bin_of(float s) {
    int b = (int)((s - TH) * BIN_SCALE);
    if (b < 0) b = 0;
    if (b > NBINS - 1) b = NBINS - 1;
    return b;
}

// Pass 1: per-image histogram of candidate sigmoid values.
__global__ void k_hist(const float* __restrict__ sCls, int* __restrict__ hist, int tot) {
    int r = blockIdx.x * blockDim.x + threadIdx.x;
    if (r >= tot) return;
    float x = sCls[r];
    if (x > XMIN) {
        float s = sigmoid_rn(x);
        if (s > TH) {
            int n = r / PER_IMG;
            atomicAdd(&hist[n * NBINS + bin_of(s)], 1);
        }
    }
}

// Per image: suffix-sum the histogram, find highest bin b with suffix(b) >= K.
__global__ void k_cutoff(const int* __restrict__ hist, int* __restrict__ cutoffs, int K) {
    __shared__ int suf[NBINS];
    __shared__ int tot[THREADS];
    int n = blockIdx.x, t = threadIdx.x;
    const int CH = NBINS / THREADS;    // 8
    int base = t * CH;
    int run = 0;
    for (int i = CH - 1; i >= 0; --i) {
        run += hist[n * NBINS + base + i];
        suf[base + i] = run;           // local suffix within chunk
    }
    int myTot = run;
    tot[t] = run;
    __syncthreads();
    // inclusive suffix scan of chunk totals (Hillis-Steele)
    for (int d = 1; d < THREADS; d <<= 1) {
        int v = (t + d < THREADS) ? tot[t + d] : 0;
        __syncthreads();
        tot[t] += v;
        __syncthreads();
    }
    int add = tot[t] - myTot;          // sum of chunks strictly after t
    for (int i = 0; i < CH; ++i) suf[base + i] += add;
    __syncthreads();
    if (t == 0 && suf[0] < K) cutoffs[n] = 0;   // fewer than K candidates total
    for (int i = 0; i < CH; ++i) {
        int b = base + i;
        int sb = suf[b];
        int sb1 = (b + 1 < NBINS) ? suf[b + 1] : 0;
        if (sb >= K && sb1 < K) cutoffs[n] = b; // unique b -> no race
    }
}

// Pass 2: compact candidates at/above the cutoff bin into per-image key buffers.
// key = (sigmoid_bits << 32) | ~flat_idx  -> descending sort == (value desc, idx asc)
__global__ void k_collect(const float* __restrict__ sCls,
                          const int* __restrict__ cutoffs,
                          int* __restrict__ cnt,
                          unsigned long long* __restrict__ coll, int tot) {
    int r = blockIdx.x * blockDim.x + threadIdx.x;
    if (r >= tot) return;
    float x = sCls[r];
    if (x <= XMIN) return;
    float s = sigmoid_rn(x);
    if (s <= TH) return;
    int n = r / PER_IMG;
    if (bin_of(s) < cutoffs[n]) return;
    int ri = r - n * PER_IMG;
    int c  = ri >> 14;                 // / HW_
    int hw = ri & (HW_ - 1);
    int idx = hw * C_CLS + c;          // flat index in [HW*C) permuted order
    int slot = atomicAdd(&cnt[n], 1);
    if (slot < CAP) {
        unsigned int sb = __float_as_uint(s);
        coll[n * CAP + slot] = ((unsigned long long)sb << 32) | (unsigned int)(~idx);
    }
}

// Per image: bitonic-sort keys descending in LDS, decode top-K.
__global__ __launch_bounds__(1024) void k_sort_decode(
        const unsigned long long* __restrict__ coll,
        const int* __restrict__ cnt,
        const float* __restrict__ sReg,
        const float* __restrict__ anchors,
        float* __restrict__ out, int N, int K) {
    __shared__ unsigned long long a[SORTN];
    int n = blockIdx.x, t = threadIdx.x;
    int m = cnt[n]; if (m > CAP) m = CAP;
    for (int i = t; i < SORTN; i += blockDim.x)
        a[i] = (i < m) ? coll[n * CAP + i] : 0ULL;
    __syncthreads();
    for (int k = 2; k <= SORTN; k <<= 1) {
        for (int j = k >> 1; j > 0; j >>= 1) {
            for (int i = t; i < SORTN; i += blockDim.x) {
                int l = i ^ j;
                if (l > i) {
                    unsigned long long ai = a[i], al = a[l];
                    bool up = ((i & k) == 0);              // descending overall
                    bool sw = up ? (ai < al) : (ai > al);
                    if (sw) { a[i] = al; a[l] = ai; }
                }
            }
            __syncthreads();
        }
    }
    float* det    = out;
    float* labels = out + (size_t)N * K * 16;
    float* scores = labels + (size_t)N * K;
    for (int kk = t; kk < K; kk += blockDim.x) {
        unsigned long long key = a[kk];
        float s = __uint_as_float((unsigned int)(key >> 32));
        float* drow = det + (size_t)(n * K + kk) * 16;
        if (s > TH) {
            int idx = (int)(~(unsigned int)key);
            int loc = idx / C_CLS;
            int c   = idx - loc * C_CLS;
            float a0 = anchors[loc * 4 + 0], a1 = anchors[loc * 4 + 1];
            float a2 = anchors[loc * 4 + 2], a3 = anchors[loc * 4 + 3];
            float wa = a2 - a0, ha = a3 - a1;
            float cx = 0.5f * (a0 + a2), cy = 0.5f * (a1 + a3);
            // sReg[n][c*16+j][h][w] = sReg[((n*C + c)*16 + j)*HW + loc]
            const float* rbase = sReg + (size_t)((n * C_CLS + c) * 16) * HW_ + loc;
            #pragma unroll
            for (int j = 0; j < 8; ++j)
                drow[j] = rbase[(size_t)j * HW_] * wa + cx;
            #pragma unroll
            for (int j = 0; j < 8; ++j)
                drow[8 + j] = rbase[(size_t)(8 + j) * HW_] * ha + cy;
            labels[n * K + kk] = (float)(c + 1);
            scores[n * K + kk] = sqrtf(s);
        } else {
            #pragma unroll
            for (int j = 0; j < 16; ++j) drow[j] = 0.0f;
            labels[n * K + kk] = 0.0f;
            scores[n * K + kk] = 0.0f;
        }
    }
}

extern "C" void kernel_launch(void* const* d_in, const int* in_sizes, int n_in,
                              void* d_out, int out_size, void* d_ws, size_t ws_size,
                              hipStream_t stream) {
    const float* sCls    = (const float*)d_in[0];
    const float* sReg    = (const float*)d_in[1];
    const float* anchors = (const float*)d_in[2];
    int tot = in_sizes[0];                 // N*C*H*W
    int N   = tot / PER_IMG;               // 16
    int K   = out_size / (N * 18);         // 1000 (16 det + 1 label + 1 score)

    // workspace layout
    size_t hist_bytes = (size_t)N * NBINS * sizeof(int);
    char* ws = (char*)d_ws;
    int* hist    = (int*)ws;
    int* cnt     = (int*)(ws + hist_bytes);
    int* cutoffs = cnt + N;
    size_t coll_off = ((hist_bytes + (size_t)N * 8) + 255) & ~(size_t)255;
    unsigned long long* coll = (unsigned long long*)(ws + coll_off);

    hipMemsetAsync(d_ws, 0, coll_off, stream);   // zero hist + cnt (+cutoffs)

    int blocks = (tot + THREADS - 1) / THREADS;
    k_hist<<<blocks, THREADS, 0, stream>>>(sCls, hist, tot);
    k_cutoff<<<N, THREADS, 0, stream>>>(hist, cutoffs, K);
    k_collect<<<blocks, THREADS, 0, stream>>>(sCls, cutoffs, cnt, coll, tot);
    k_sort_decode<<<N, 1024, 0, stream>>>(coll, cnt, sReg, anchors, (float*)d_out, N, K);
}

// Round 3
// 898.999 us; speedup vs baseline: 1.4660x; 1.4660x over previous
//
#include <hip/hip_runtime.h>
#include <stdint.h>
#include <math.h>

#define THREADS 256
#define NBINS   2048
#define CAP     2048
#define SORTN   2048
#define C_CLS   30
#define H_      128
#define W_      128
#define HW_     (H_*W_)            // 16384
#define PER_IMG (C_CLS*HW_)        // 491520 (divisible by 1024 -> block-uniform image id)
#define TH      0.3f
#define XLO     -0.8473f           // conservative logit pre-filter (< true f32 boundary -0.847297)
#define BIN_LO  -0.85f
#define BIN_HI  3.35f
#define BIN_SCALE ((float)NBINS / (BIN_HI - BIN_LO))

// exact-as-before sigmoid (f64 -> correctly-rounded f32); only used in decode (16k calls)
__device__ __forceinline__ float sigmoid_rn(float x) {
    return (float)(1.0 / (1.0 + exp(-(double)x)));
}

__device__ __forceinline__ int bin_of_x(float x) {
    int b = (int)((x - BIN_LO) * BIN_SCALE);
    if (b < 0) b = 0;
    if (b > NBINS - 1) b = NBINS - 1;
    return b;
}

// monotone float -> uint map (sign-flip trick); larger logit => larger key
__device__ __forceinline__ unsigned mapf(float x) {
    unsigned u = __float_as_uint(x);
    return (u & 0x80000000u) ? ~u : (u ^ 0x80000000u);
}
__device__ __forceinline__ float unmapf(unsigned m) {
    unsigned u = (m & 0x80000000u) ? (m ^ 0x80000000u) : ~m;
    return __uint_as_float(u);
}

// Pass 1: per-image histogram of candidate LOGITS (no transcendentals).
__global__ void k_hist(const float4* __restrict__ sCls, int* __restrict__ hist, int tot4) {
    int i = blockIdx.x * blockDim.x + threadIdx.x;
    if (i >= tot4) return;
    float4 v = sCls[i];
    int n = (int)(((long long)i * 4) / PER_IMG);
    int* h = hist + n * NBINS;
    if (v.x > XLO) atomicAdd(&h[bin_of_x(v.x)], 1);
    if (v.y > XLO) atomicAdd(&h[bin_of_x(v.y)], 1);
    if (v.z > XLO) atomicAdd(&h[bin_of_x(v.z)], 1);
    if (v.w > XLO) atomicAdd(&h[bin_of_x(v.w)], 1);
}

// Per image: suffix-sum the histogram, find highest bin b with suffix(b) >= K.
__global__ void k_cutoff(const int* __restrict__ hist, int* __restrict__ cutoffs, int K) {
    __shared__ int suf[NBINS];
    __shared__ int tot[THREADS];
    int n = blockIdx.x, t = threadIdx.x;
    const int CH = NBINS / THREADS;    // 8
    int base = t * CH;
    int run = 0;
    for (int i = CH - 1; i >= 0; --i) {
        run += hist[n * NBINS + base + i];
        suf[base + i] = run;
    }
    int myTot = run;
    tot[t] = run;
    __syncthreads();
    for (int d = 1; d < THREADS; d <<= 1) {
        int v = (t + d < THREADS) ? tot[t + d] : 0;
        __syncthreads();
        tot[t] += v;
        __syncthreads();
    }
    int add = tot[t] - myTot;
    for (int i = 0; i < CH; ++i) suf[base + i] += add;
    __syncthreads();
    if (t == 0 && suf[0] < K) cutoffs[n] = 0;
    for (int i = 0; i < CH; ++i) {
        int b = base + i;
        int sb = suf[b];
        int sb1 = (b + 1 < NBINS) ? suf[b + 1] : 0;
        if (sb >= K && sb1 < K) cutoffs[n] = b;
    }
}

// Pass 2: compact candidates at/above cutoff bin. Block-aggregated slot allocation:
// LDS counter for intra-block rank, ONE global atomicAdd per block for the base.
__global__ void k_collect(const float4* __restrict__ sCls,
                          const int* __restrict__ cutoffs,
                          int* __restrict__ cnt,
                          unsigned long long* __restrict__ coll, int tot4) {
    __shared__ int lcnt;
    __shared__ int lbase;
    int i   = blockIdx.x * blockDim.x + threadIdx.x;
    int tid = threadIdx.x;
    int nblk = (int)(((long long)blockIdx.x * blockDim.x * 4) / PER_IMG); // block-uniform image
    if (tid == 0) lcnt = 0;
    __syncthreads();

    int nq = 0;
    unsigned long long keys[4];
    int slot0 = 0;
    if (i < tot4) {
        float4 v = sCls[i];
        int r4 = i * 4;
        int co = cutoffs[nblk];
        int ri = r4 - nblk * PER_IMG;
        float xs[4] = {v.x, v.y, v.z, v.w};
        #pragma unroll
        for (int j = 0; j < 4; ++j) {
            float x = xs[j];
            if (x > XLO && bin_of_x(x) >= co) {
                int rr = ri + j;
                int c  = rr >> 14;            // / HW_
                int hw = rr & (HW_ - 1);
                int idx = hw * C_CLS + c;     // flat index in permuted [HW*C) order
                keys[nq] = ((unsigned long long)mapf(x) << 32) | (unsigned)(~idx);
                ++nq;
            }
        }
        if (nq) slot0 = atomicAdd(&lcnt, nq);   // LDS atomic: cheap
    }
    __syncthreads();
    if (tid == 0) lbase = (lcnt > 0) ? atomicAdd(&cnt[nblk], lcnt) : 0;
    __syncthreads();
    for (int j = 0; j < nq; ++j) {
        int s = lbase + slot0 + j;
        if (s < CAP) coll[nblk * CAP + s] = keys[j];
    }
}

// Per image: bitonic-sort keys descending in LDS, decode top-K (sigmoid only here).
__global__ __launch_bounds__(1024) void k_sort_decode(
        const unsigned long long* __restrict__ coll,
        const int* __restrict__ cnt,
        const float* __restrict__ sReg,
        const float* __restrict__ anchors,
        float* __restrict__ out, int N, int K) {
    __shared__ unsigned long long a[SORTN];
    int n = blockIdx.x, t = threadIdx.x;
    int m = cnt[n]; if (m > CAP) m = CAP;
    for (int i = t; i < SORTN; i += blockDim.x)
        a[i] = (i < m) ? coll[n * CAP + i] : 0ULL;
    __syncthreads();
    for (int k = 2; k <= SORTN; k <<= 1) {
        for (int j = k >> 1; j > 0; j >>= 1) {
            for (int i = t; i < SORTN; i += blockDim.x) {
                int l = i ^ j;
                if (l > i) {
                    unsigned long long ai = a[i], al = a[l];
                    bool up = ((i & k) == 0);              // descending overall
                    bool sw = up ? (ai < al) : (ai > al);
                    if (sw) { a[i] = al; a[l] = ai; }
                }
            }
            __syncthreads();
        }
    }
    float* det    = out;
    float* labels = out + (size_t)N * K * 16;
    float* scores = labels + (size_t)N * K;
    for (int kk = t; kk < K; kk += blockDim.x) {
        unsigned long long key = a[kk];
        float x = unmapf((unsigned)(key >> 32));   // padding key 0 -> NaN -> invalid path
        float s = sigmoid_rn(x);
        float* drow = det + (size_t)(n * K + kk) * 16;
        if (s > TH) {
            int idx = (int)(~(unsigned int)key);
            int loc = idx / C_CLS;
            int c   = idx - loc * C_CLS;
            float a0 = anchors[loc * 4 + 0], a1 = anchors[loc * 4 + 1];
            float a2 = anchors[loc * 4 + 2], a3 = anchors[loc * 4 + 3];
            float wa = a2 - a0, ha = a3 - a1;
            float cx = 0.5f * (a0 + a2), cy = 0.5f * (a1 + a3);
            const float* rbase = sReg + (size_t)((n * C_CLS + c) * 16) * HW_ + loc;
            #pragma unroll
            for (int j = 0; j < 8; ++j)
                drow[j] = rbase[(size_t)j * HW_] * wa + cx;
            #pragma unroll
            for (int j = 0; j < 8; ++j)
                drow[8 + j] = rbase[(size_t)(8 + j) * HW_] * ha + cy;
            labels[n * K + kk] = (float)(c + 1);
            scores[n * K + kk] = sqrtf(s);
        } else {
            #pragma unroll
            for (int j = 0; j < 16; ++j) drow[j] = 0.0f;
            labels[n * K + kk] = 0.0f;
            scores[n * K + kk] = 0.0f;
        }
    }
}

extern "C" void kernel_launch(void* const* d_in, const int* in_sizes, int n_in,
                              void* d_out, int out_size, void* d_ws, size_t ws_size,
                              hipStream_t stream) {
    const float* sCls    = (const float*)d_in[0];
    const float* sReg    = (const float*)d_in[1];
    const float* anchors = (const float*)d_in[2];
    int tot = in_sizes[0];                 // N*C*H*W
    int N   = tot / PER_IMG;               // 16
    int K   = out_size / (N * 18);         // 1000

    size_t hist_bytes = (size_t)N * NBINS * sizeof(int);
    char* ws = (char*)d_ws;
    int* hist    = (int*)ws;
    int* cnt     = (int*)(ws + hist_bytes);
    int* cutoffs = cnt + N;
    size_t coll_off = ((hist_bytes + (size_t)N * 8) + 255) & ~(size_t)255;
    unsigned long long* coll = (unsigned long long*)(ws + coll_off);

    hipMemsetAsync(d_ws, 0, coll_off, stream);   // zero hist + cnt + cutoffs

    int tot4 = tot / 4;
    int blocks4 = (tot4 + THREADS - 1) / THREADS;
    k_hist<<<blocks4, THREADS, 0, stream>>>((const float4*)sCls, hist, tot4);
    k_cutoff<<<N, THREADS, 0, stream>>>(hist, cutoffs, K);
    k_collect<<<blocks4, THREADS, 0, stream>>>((const float4*)sCls, cutoffs, cnt, coll, tot4);
    k_sort_decode<<<N, 1024, 0, stream>>>(coll, cnt, sReg, anchors, (float*)d_out, N, K);
}